// Round 6
// baseline (610.770 us; speedup 1.0000x reference)
//
#include <hip/hip_runtime.h>
#include <math.h>

#define B 64
#define N 16384
#define MDIM 64
#define DDIM 512
#define EPSF 1e-16f
#define NCH 16              // chunks per batch
#define CHUNK 1024          // rows per chunk
#define GRID (B * NCH)      // 1024 blocks

// ws float layout
#define K_OFF      0                        // B*64
#define SCAL_OFF   (B*64)                   // B*8: kn,beta,g,s0,s1,s2,gamma,pad
#define MS_OFF     (SCAL_OFF + B*8)         // B*NCH*2 per-chunk (max, sumexp)
#define EDGE_OFF   (MS_OFF + B*NCH*2)       // B*NCH*2 per-chunk (first,last score)
#define PSUM_OFF   (EDGE_OFF + B*NCH*2)     // B*NCH per-chunk pow partial sums
#define PART_OFF   (PSUM_OFF + B*NCH)       // GRID*64 r partials (normalized)
#define CNT_OFF    (PART_OFF + GRID*64)     // 2*B ints: cntA[b], cntB[b]

// 16-lane (DPP row) sum reduction: row_ror 8,4,2,1. All 16 lanes end with the sum.
__device__ __forceinline__ float rowsum16(float x) {
    float t;
    t = __int_as_float(__builtin_amdgcn_update_dpp(0, __float_as_int(x), 0x128, 0xF, 0xF, true)); x += t;
    t = __int_as_float(__builtin_amdgcn_update_dpp(0, __float_as_int(x), 0x124, 0xF, 0xF, true)); x += t;
    t = __int_as_float(__builtin_amdgcn_update_dpp(0, __float_as_int(x), 0x122, 0xF, 0xF, true)); x += t;
    t = __int_as_float(__builtin_amdgcn_update_dpp(0, __float_as_int(x), 0x121, 0xF, 0xF, true)); x += t;
    return x;
}

// Per-batch barrier: all `target` blocks of a batch rendezvous on flag.
__device__ __forceinline__ void batch_barrier(int* flag, int target) {
    __syncthreads();
    __threadfence();                       // release: publish prior global writes
    if (threadIdx.x == 0) {
        atomicAdd(flag, 1);                // device-scope by default
        while (__hip_atomic_load(flag, __ATOMIC_ACQUIRE, __HIP_MEMORY_SCOPE_AGENT) < target)
            __builtin_amdgcn_s_sleep(4);
    }
    __syncthreads();
    __threadfence();                       // acquire side for all threads
}

// ---------- K1: o = c@W.T + b, activations; zero batch counters ----------
__global__ __launch_bounds__(256) void k1(const float* __restrict__ c,
                                          const float* __restrict__ W,
                                          const float* __restrict__ bias,
                                          float* __restrict__ ws) {
    int b = blockIdx.x;
    int tid = threadIdx.x;
    if (tid < 2) ((int*)(ws + CNT_OFF))[b * 2 + tid] = 0;   // reset flags each call
    __shared__ float cs[DDIM];
    __shared__ float osh[72];
    for (int i = tid; i < DDIM; i += 256) cs[i] = c[b * DDIM + i];
    __syncthreads();
    int wave = tid >> 6, lane = tid & 63;
    for (int j = wave; j < MDIM + 6; j += 4) {
        const float* wr = W + (size_t)j * DDIM;
        float sum = 0.f;
        for (int d = lane; d < DDIM; d += 64) sum += cs[d] * wr[d];
        for (int off = 32; off > 0; off >>= 1) sum += __shfl_xor(sum, off);
        if (lane == 0) osh[j] = sum + bias[j];
    }
    __syncthreads();
    if (tid < 64) ws[K_OFF + b * 64 + tid] = osh[tid];
    if (wave == 0) {
        float v = osh[lane];
        float sq = v * v;
        for (int off = 32; off > 0; off >>= 1) sq += __shfl_xor(sq, off);
        if (lane == 0) {
            float kn = sqrtf(sq);
            float ob = osh[64], og = osh[65], os0 = osh[66], os1 = osh[67],
                  os2 = osh[68], ogm = osh[69];
            float beta  = fmaxf(ob, 0.f) + log1pf(expf(-fabsf(ob)));
            float g     = 1.f / (1.f + expf(-og));
            float mx    = fmaxf(os0, fmaxf(os1, os2));
            float e0 = expf(os0 - mx), e1 = expf(os1 - mx), e2 = expf(os2 - mx);
            float es = e0 + e1 + e2;
            float gamma = 1.f + fmaxf(ogm, 0.f) + log1pf(expf(-fabsf(ogm)));
            float* sc = ws + SCAL_OFF + b * 8;
            sc[0] = kn; sc[1] = beta; sc[2] = g;
            sc[3] = e0 / es; sc[4] = e1 / es; sc[5] = e2 / es;
            sc[6] = gamma;
        }
    }
}

// ---------- MEGA: scores -> (batch barrier) -> w_g/pow -> (batch barrier) -> r pass ----------
__global__ __launch_bounds__(256, 4) void mega(const float* __restrict__ mem,
                                               const float* __restrict__ w_prev,
                                               float* __restrict__ ws,
                                               float* __restrict__ w_out,
                                               float* __restrict__ part) {
    int cid = blockIdx.x;
    int b = cid >> 4, ch = cid & (NCH - 1);
    int tid = threadIdx.x, wave = tid >> 6, lane = tid & 63;
    int grp = tid >> 4, ll = tid & 15;
    __shared__ float scbuf[CHUNK];     // this chunk's scores
    __shared__ float wgL[CHUNK + 2];   // w_g with halo
    __shared__ float wpl[CHUNK];       // w_pow (then normalized w)
    __shared__ float ldsr[16][64];
    __shared__ float red[8];
    __shared__ float ks[64];
    __shared__ float kb2[2];
    int* cntA = (int*)(ws + CNT_OFF);
    int* cntB = cntA + B;
    const int row0 = ch * CHUNK;
    const float* sl = ws + SCAL_OFF + b * 8;

    if (tid < 64) ks[tid] = ws[K_OFF + b * 64 + tid];
    if (tid == 64) kb2[0] = sl[0];
    if (tid == 65) kb2[1] = sl[1];
    __syncthreads();
    float kn = kb2[0], beta = kb2[1];
    float k0 = ks[ll * 4], k1v = ks[ll * 4 + 1], k2v = ks[ll * 4 + 2], k3v = ks[ll * 4 + 3];

    // ---- Phase A: scores for this chunk (memory pass 1) ----
    #pragma unroll 8
    for (int it = 0; it < CHUNK / 16; ++it) {
        int lrow = it * 16 + grp;
        float4 v = *reinterpret_cast<const float4*>(
            mem + ((size_t)b * N + row0 + lrow) * MDIM + ll * 4);
        float dot = v.x * k0 + v.y * k1v + v.z * k2v + v.w * k3v;
        float sq  = v.x * v.x + v.y * v.y + v.z * v.z + v.w * v.w;
        dot = rowsum16(dot);
        sq  = rowsum16(sq);
        if (ll == 0) {
            float score = beta * (dot / (kn * sqrtf(sq) + EPSF));
            scbuf[lrow] = score;
            if (lrow == 0)
                ws[EDGE_OFF + ((size_t)b * NCH + ch) * 2]     = score;
            if (lrow == CHUNK - 1)
                ws[EDGE_OFF + ((size_t)b * NCH + ch) * 2 + 1] = score;
        }
    }
    __syncthreads();

    // chunk stats: max then sum(exp(.-max))
    float vr[4];
    float m = -1e30f;
    #pragma unroll
    for (int j = 0; j < 4; ++j) {
        vr[j] = scbuf[tid + 256 * j];
        m = fmaxf(m, vr[j]);
    }
    #pragma unroll
    for (int off = 32; off > 0; off >>= 1) m = fmaxf(m, __shfl_xor(m, off));
    if (lane == 0) red[wave] = m;
    __syncthreads();
    m = fmaxf(fmaxf(red[0], red[1]), fmaxf(red[2], red[3]));
    float s = 0.f;
    #pragma unroll
    for (int j = 0; j < 4; ++j) s += __expf(vr[j] - m);
    #pragma unroll
    for (int off = 32; off > 0; off >>= 1) s += __shfl_xor(s, off);
    if (lane == 0) red[4 + wave] = s;
    __syncthreads();
    if (tid == 0) {
        ws[MS_OFF + ((size_t)b * NCH + ch) * 2]     = m;
        ws[MS_OFF + ((size_t)b * NCH + ch) * 2 + 1] = red[4] + red[5] + red[6] + red[7];
    }

    batch_barrier(cntA + b, NCH);

    // ---- Phase B: combine stats (redundant per thread), w_g + shift + pow ----
    float g = sl[2], s0 = sl[3], s1 = sl[4], s2 = sl[5], gamma = sl[6];
    float mx = -1e30f, ssum = 0.f;
    #pragma unroll
    for (int i = 0; i < NCH; ++i) {
        float mi = ws[MS_OFF + ((size_t)b * NCH + i) * 2];
        float si = ws[MS_OFF + ((size_t)b * NCH + i) * 2 + 1];
        float M = fmaxf(mx, mi);
        ssum = ssum * __expf(mx - M) + si * __expf(mi - M);
        mx = M;
    }
    float inv = 1.f / ssum;
    const float* wp = w_prev + (size_t)b * N;
    #pragma unroll
    for (int j = 0; j < 4; ++j) {
        int i = tid + 256 * j;
        wgL[i + 1] = g * (__expf(scbuf[i] - mx) * inv) + (1.f - g) * wp[row0 + i];
    }
    if (tid == 0) {
        float scL = ws[EDGE_OFF + ((size_t)b * NCH + ((ch + NCH - 1) & (NCH - 1))) * 2 + 1];
        wgL[0] = g * (__expf(scL - mx) * inv) + (1.f - g) * wp[(row0 - 1) & (N - 1)];
    }
    if (tid == 255) {
        float scR = ws[EDGE_OFF + ((size_t)b * NCH + ((ch + 1) & (NCH - 1))) * 2];
        wgL[CHUNK + 1] = g * (__expf(scR - mx) * inv) + (1.f - g) * wp[(row0 + CHUNK) & (N - 1)];
    }
    __syncthreads();

    float sp = 0.f;
    #pragma unroll
    for (int j = 0; j < 4; ++j) {
        int i = tid + 256 * j;
        float wt = s0 * wgL[i] + s1 * wgL[i + 1] + s2 * wgL[i + 2];
        float p = __expf(gamma * __logf(wt));   // wt in (0,1]; 0 -> 0 correctly
        wpl[i] = p;
        sp += p;
    }
    #pragma unroll
    for (int off = 32; off > 0; off >>= 1) sp += __shfl_xor(sp, off);
    if (lane == 0) red[wave] = sp;
    __syncthreads();
    if (tid == 0)
        ws[PSUM_OFF + (size_t)b * NCH + ch] = red[0] + red[1] + red[2] + red[3];

    batch_barrier(cntB + b, NCH);

    // ---- Phase C: normalize w in LDS, write w, r-partial (memory pass 2) ----
    float spTot = 0.f;
    #pragma unroll
    for (int i = 0; i < NCH; ++i) spTot += ws[PSUM_OFF + (size_t)b * NCH + i];
    float invp = 1.f / (spTot + EPSF);
    float* wo = w_out + (size_t)b * N + row0;
    #pragma unroll
    for (int j = 0; j < 4; ++j) {
        int i = tid + 256 * j;
        float wv = wpl[i] * invp;
        wpl[i] = wv;
        wo[i] = wv;
    }
    __syncthreads();

    float4 acc = make_float4(0.f, 0.f, 0.f, 0.f);
    #pragma unroll 8
    for (int it = 0; it < CHUNK / 16; ++it) {
        int lrow = it * 16 + grp;
        float wv = wpl[lrow];
        float4 v = *reinterpret_cast<const float4*>(
            mem + ((size_t)b * N + row0 + lrow) * MDIM + ll * 4);
        acc.x += wv * v.x; acc.y += wv * v.y; acc.z += wv * v.z; acc.w += wv * v.w;
    }
    ldsr[grp][ll * 4 + 0] = acc.x;
    ldsr[grp][ll * 4 + 1] = acc.y;
    ldsr[grp][ll * 4 + 2] = acc.z;
    ldsr[grp][ll * 4 + 3] = acc.w;
    __syncthreads();
    if (tid < 64) {
        float sacc = 0.f;
        #pragma unroll
        for (int gi = 0; gi < 16; ++gi) sacc += ldsr[gi][tid];
        part[(size_t)cid * 64 + tid] = sacc;
    }
}

// ---------- KRR: reduce normalized partials -> r ----------
__global__ __launch_bounds__(64) void krr(const float* __restrict__ part,
                                          float* __restrict__ r) {
    int b = blockIdx.x, m = threadIdx.x;
    float s = 0.f;
    #pragma unroll
    for (int c = 0; c < NCH; ++c) s += part[((size_t)b * NCH + c) * 64 + m];
    r[b * 64 + m] = s;
}

extern "C" void kernel_launch(void* const* d_in, const int* in_sizes, int n_in,
                              void* d_out, int out_size, void* d_ws, size_t ws_size,
                              hipStream_t stream) {
    const float* c      = (const float*)d_in[0];
    const float* w_prev = (const float*)d_in[1];
    const float* mem    = (const float*)d_in[2];
    const float* W      = (const float*)d_in[3];
    const float* bias   = (const float*)d_in[4];
    float* out = (float*)d_out;
    float* r_out = out;                 // B*M
    float* w_out = out + B * MDIM;      // B*N
    float* ws = (float*)d_ws;
    float* part = ws + PART_OFF;

    k1<<<B, 256, 0, stream>>>(c, W, bias, ws);

    void* args[] = { (void*)&mem, (void*)&w_prev, (void*)&ws, (void*)&w_out, (void*)&part };
    hipError_t e = hipLaunchCooperativeKernel((void*)mega, dim3(GRID), dim3(256),
                                              args, 0, stream);
    if (e != hipSuccess) {
        // fallback: plain launch (grid == exact co-residency capacity at 4 blk/CU)
        mega<<<GRID, 256, 0, stream>>>(mem, w_prev, ws, w_out, part);
    }

    krr<<<B, 64, 0, stream>>>(part, r_out);
}

// Round 7
// 111.013 us; speedup vs baseline: 5.5018x; 5.5018x over previous
//
#include <hip/hip_runtime.h>
#include <math.h>

#define B 64
#define N 16384
#define MDIM 64
#define DDIM 512
#define EPSF 1e-16f
#define NCH 32              // chunks per batch
#define CHUNK 512           // rows per chunk
#define GRID (B * NCH)      // 2048 blocks

// ws float layout
#define K_OFF      0                        // B*64
#define SCAL_OFF   (B*64)                   // B*8: kn,beta,g,s0,s1,s2,gamma,pad
#define SCORE_OFF  (SCAL_OFF + B*8)         // B*N scores
#define MS_OFF     (SCORE_OFF + B*N)        // B*NCH*2 per-chunk (max, sumexp)
#define PSUM_OFF   (MS_OFF + B*NCH*2)       // B*NCH per-chunk pow partial sums
#define PART_OFF   (PSUM_OFF + B*NCH)       // GRID*64 r partials (unnormalized)

// 16-lane (DPP row) sum reduction: row_ror 8,4,2,1. All 16 lanes end with the sum.
__device__ __forceinline__ float rowsum16(float x) {
    float t;
    t = __int_as_float(__builtin_amdgcn_update_dpp(0, __float_as_int(x), 0x128, 0xF, 0xF, true)); x += t;
    t = __int_as_float(__builtin_amdgcn_update_dpp(0, __float_as_int(x), 0x124, 0xF, 0xF, true)); x += t;
    t = __int_as_float(__builtin_amdgcn_update_dpp(0, __float_as_int(x), 0x122, 0xF, 0xF, true)); x += t;
    t = __int_as_float(__builtin_amdgcn_update_dpp(0, __float_as_int(x), 0x121, 0xF, 0xF, true)); x += t;
    return x;
}

// ---------- K1: o = c@W.T + b, activations ----------
__global__ __launch_bounds__(256) void k1(const float* __restrict__ c,
                                          const float* __restrict__ W,
                                          const float* __restrict__ bias,
                                          float* __restrict__ ws) {
    int b = blockIdx.x;
    __shared__ float cs[DDIM];
    __shared__ float osh[72];
    int tid = threadIdx.x;
    for (int i = tid; i < DDIM; i += 256) cs[i] = c[b * DDIM + i];
    __syncthreads();
    int wave = tid >> 6, lane = tid & 63;
    for (int j = wave; j < MDIM + 6; j += 4) {
        const float* wr = W + (size_t)j * DDIM;
        float sum = 0.f;
        for (int d = lane; d < DDIM; d += 64) sum += cs[d] * wr[d];
        for (int off = 32; off > 0; off >>= 1) sum += __shfl_xor(sum, off);
        if (lane == 0) osh[j] = sum + bias[j];
    }
    __syncthreads();
    if (tid < 64) ws[K_OFF + b * 64 + tid] = osh[tid];
    if (wave == 0) {
        float v = osh[lane];
        float sq = v * v;
        for (int off = 32; off > 0; off >>= 1) sq += __shfl_xor(sq, off);
        if (lane == 0) {
            float kn = sqrtf(sq);
            float ob = osh[64], og = osh[65], os0 = osh[66], os1 = osh[67],
                  os2 = osh[68], ogm = osh[69];
            float beta  = fmaxf(ob, 0.f) + log1pf(expf(-fabsf(ob)));
            float g     = 1.f / (1.f + expf(-og));
            float mx    = fmaxf(os0, fmaxf(os1, os2));
            float e0 = expf(os0 - mx), e1 = expf(os1 - mx), e2 = expf(os2 - mx);
            float es = e0 + e1 + e2;
            float gamma = 1.f + fmaxf(ogm, 0.f) + log1pf(expf(-fabsf(ogm)));
            float* sc = ws + SCAL_OFF + b * 8;
            sc[0] = kn; sc[1] = beta; sc[2] = g;
            sc[3] = e0 / es; sc[4] = e1 / es; sc[5] = e2 / es;
            sc[6] = gamma;
        }
    }
}

// ---------- K2: scores + per-chunk softmax stats ----------
__global__ __launch_bounds__(256) void k2(const float* __restrict__ mem,
                                          float* __restrict__ ws) {
    int b = blockIdx.x >> 5, chunk = blockIdx.x & 31;
    __shared__ float ks[64];
    __shared__ float kb2[2];
    __shared__ float scbuf[CHUNK];
    int tid = threadIdx.x;
    if (tid < 64) ks[tid] = ws[K_OFF + b * 64 + tid];
    if (tid == 64) kb2[0] = ws[SCAL_OFF + b * 8 + 0];
    if (tid == 65) kb2[1] = ws[SCAL_OFF + b * 8 + 1];
    __syncthreads();
    float kn = kb2[0], beta = kb2[1];
    int grp = tid >> 4, ll = tid & 15;
    float k0 = ks[ll * 4], k1v = ks[ll * 4 + 1], k2v = ks[ll * 4 + 2], k3v = ks[ll * 4 + 3];
    int row0 = chunk * CHUNK;
    #pragma unroll 8
    for (int it = 0; it < CHUNK / 16; ++it) {
        int lrow = it * 16 + grp;
        float4 v = *reinterpret_cast<const float4*>(
            mem + ((size_t)b * N + row0 + lrow) * MDIM + ll * 4);
        float dot = v.x * k0 + v.y * k1v + v.z * k2v + v.w * k3v;
        float sq  = v.x * v.x + v.y * v.y + v.z * v.z + v.w * v.w;
        dot = rowsum16(dot);
        sq  = rowsum16(sq);
        if (ll == 0)
            scbuf[lrow] = beta * (dot / (kn * sqrtf(sq) + EPSF));
    }
    __syncthreads();
    // coalesced score write + chunk stats from wave 0
    {
        float s0v = scbuf[tid], s1v = scbuf[tid + 256];
        float* sco = ws + SCORE_OFF + (size_t)b * N + row0;
        sco[tid] = s0v;
        sco[tid + 256] = s1v;
    }
    if (tid < 64) {
        float vr[8];
        float m = -1e30f;
        #pragma unroll
        for (int j = 0; j < 8; ++j) {
            vr[j] = scbuf[tid + 64 * j];
            m = fmaxf(m, vr[j]);
        }
        #pragma unroll
        for (int off = 32; off > 0; off >>= 1) m = fmaxf(m, __shfl_xor(m, off));
        float s = 0.f;
        #pragma unroll
        for (int j = 0; j < 8; ++j) s += __expf(vr[j] - m);
        #pragma unroll
        for (int off = 32; off > 0; off >>= 1) s += __shfl_xor(s, off);
        if (tid == 0) {
            ws[MS_OFF + ((size_t)b * NCH + chunk) * 2]     = m;
            ws[MS_OFF + ((size_t)b * NCH + chunk) * 2 + 1] = s;
        }
    }
}

// ---------- KRW: inline stats combine + w_g/shift/pow + r-partial memory pass ----------
__global__ __launch_bounds__(256) void krw(const float* __restrict__ mem,
                                           const float* __restrict__ w_prev,
                                           float* __restrict__ ws,
                                           float* __restrict__ w_out,
                                           float* __restrict__ part) {
    int b = blockIdx.x >> 5, chunk = blockIdx.x & 31;
    int tid = threadIdx.x, wave = tid >> 6, lane = tid & 63;
    __shared__ float wgL[CHUNK + 2];   // w_g halo buffer
    __shared__ float wpl[CHUNK];       // w_pow (unnormalized)
    __shared__ float lds[16][64];      // r partial reduce
    __shared__ float red[4];
    const float* sl = ws + SCAL_OFF + b * 8;
    float g = sl[2], s0 = sl[3], s1 = sl[4], s2 = sl[5], gamma = sl[6];

    // combine per-chunk (m,s) -> (mx, inv), redundantly per thread (32 iters)
    float mx = -1e30f, ssum = 0.f;
    const float* msp = ws + MS_OFF + (size_t)b * NCH * 2;
    #pragma unroll
    for (int i = 0; i < NCH; ++i) {
        float mi = msp[i * 2], si = msp[i * 2 + 1];
        float M = fmaxf(mx, mi);
        ssum = ssum * __expf(mx - M) + si * __expf(mi - M);
        mx = M;
    }
    float inv = 1.f / ssum;

    const float* sc = ws + SCORE_OFF + (size_t)b * N;
    const float* wp = w_prev + (size_t)b * N;
    int row0 = chunk * CHUNK;

    // w_g(row) = g * softmax + (1-g) * w_prev, rows row0-1 .. row0+CHUNK
    {
        int r0 = row0 + tid;
        wgL[tid + 1]   = g * (__expf(sc[r0] - mx) * inv) + (1.f - g) * wp[r0];
        int r1 = row0 + tid + 256;
        wgL[tid + 257] = g * (__expf(sc[r1] - mx) * inv) + (1.f - g) * wp[r1];
        if (tid == 0) {
            int rl = (row0 - 1) & (N - 1);
            wgL[0] = g * (__expf(sc[rl] - mx) * inv) + (1.f - g) * wp[rl];
        }
        if (tid == 255) {
            int rr = (row0 + CHUNK) & (N - 1);
            wgL[CHUNK + 1] = g * (__expf(sc[rr] - mx) * inv) + (1.f - g) * wp[rr];
        }
    }
    __syncthreads();

    // shift + pow; stage w_pow in LDS and to w_out (unnormalized)
    float wt0 = s0 * wgL[tid]       + s1 * wgL[tid + 1]   + s2 * wgL[tid + 2];
    float wt1 = s0 * wgL[tid + 256] + s1 * wgL[tid + 257] + s2 * wgL[tid + 258];
    float p0 = __expf(gamma * __logf(wt0));   // wt in (0,1]; ->0 correctly
    float p1 = __expf(gamma * __logf(wt1));
    wpl[tid] = p0;
    wpl[tid + 256] = p1;
    float* wo = w_out + (size_t)b * N + row0;
    wo[tid]       = p0;
    wo[tid + 256] = p1;

    // per-chunk pow-sum
    float sp = p0 + p1;
    #pragma unroll
    for (int off = 32; off > 0; off >>= 1) sp += __shfl_xor(sp, off);
    if (lane == 0) red[wave] = sp;
    __syncthreads();
    if (tid == 0)
        ws[PSUM_OFF + (size_t)b * NCH + chunk] = red[0] + red[1] + red[2] + red[3];

    // memory pass: r partial with unnormalized w_pow from LDS
    int grp = tid >> 4, ll = tid & 15;
    float4 acc = make_float4(0.f, 0.f, 0.f, 0.f);
    #pragma unroll 8
    for (int it = 0; it < CHUNK / 16; ++it) {
        int lrow = it * 16 + grp;
        float wv = wpl[lrow];
        float4 v = *reinterpret_cast<const float4*>(
            mem + ((size_t)b * N + row0 + lrow) * MDIM + ll * 4);
        acc.x += wv * v.x; acc.y += wv * v.y; acc.z += wv * v.z; acc.w += wv * v.w;
    }
    lds[grp][ll * 4 + 0] = acc.x;
    lds[grp][ll * 4 + 1] = acc.y;
    lds[grp][ll * 4 + 2] = acc.z;
    lds[grp][ll * 4 + 3] = acc.w;
    __syncthreads();
    if (tid < 64) {
        float sacc = 0.f;
        #pragma unroll
        for (int gi = 0; gi < 16; ++gi) sacc += lds[gi][tid];
        part[(size_t)blockIdx.x * 64 + tid] = sacc;
    }
}

// ---------- KFIN: invp; finalize w in place; chunk-0 blocks also emit r ----------
__global__ __launch_bounds__(256) void kfin(const float* __restrict__ part,
                                            float* __restrict__ ws,
                                            float* __restrict__ w_out,
                                            float* __restrict__ r) {
    int b = blockIdx.x >> 5, chunk = blockIdx.x & 31;
    int tid = threadIdx.x;
    __shared__ float invps;
    if (tid < 64) {
        float s = (tid < 32) ? ws[PSUM_OFF + (size_t)b * NCH + tid] : 0.f;
        #pragma unroll
        for (int off = 32; off > 0; off >>= 1) s += __shfl_xor(s, off);
        if (tid == 0) invps = 1.f / (s + EPSF);
    }
    __syncthreads();
    float invp = invps;
    size_t base = (size_t)b * N + chunk * CHUNK;
    w_out[base + tid]       *= invp;
    w_out[base + tid + 256] *= invp;
    if (chunk == 0 && tid < 64) {
        float srr = 0.f;
        #pragma unroll
        for (int c2 = 0; c2 < NCH; ++c2)
            srr += part[((size_t)b * NCH + c2) * 64 + tid];
        r[b * 64 + tid] = srr * invp;
    }
}

extern "C" void kernel_launch(void* const* d_in, const int* in_sizes, int n_in,
                              void* d_out, int out_size, void* d_ws, size_t ws_size,
                              hipStream_t stream) {
    const float* c      = (const float*)d_in[0];
    const float* w_prev = (const float*)d_in[1];
    const float* mem    = (const float*)d_in[2];
    const float* W      = (const float*)d_in[3];
    const float* bias   = (const float*)d_in[4];
    float* out = (float*)d_out;
    float* r_out = out;                 // B*M
    float* w_out = out + B * MDIM;      // B*N (staged as w_pow, finalized by kfin)
    float* ws = (float*)d_ws;
    float* part = ws + PART_OFF;

    k1  <<<B,    256, 0, stream>>>(c, W, bias, ws);
    k2  <<<GRID, 256, 0, stream>>>(mem, ws);
    krw <<<GRID, 256, 0, stream>>>(mem, w_prev, ws, w_out, part);
    kfin<<<GRID, 256, 0, stream>>>(part, ws, w_out, r_out);
}

// Round 8
// 109.016 us; speedup vs baseline: 5.6026x; 1.0183x over previous
//
#include <hip/hip_runtime.h>
#include <math.h>

#define B 64
#define N 16384
#define MDIM 64
#define DDIM 512
#define EPSF 1e-16f
#define NCH 32              // chunks per batch
#define CHUNK 512           // rows per chunk
#define GRID (B * NCH)      // 2048 blocks

typedef float f4 __attribute__((ext_vector_type(4)));

// ws float layout
#define K_OFF      0                        // B*64
#define SCAL_OFF   (B*64)                   // B*8: kn,beta,g,s0,s1,s2,gamma,pad
#define SCORE_OFF  (SCAL_OFF + B*8)         // B*N scores
#define MS_OFF     (SCORE_OFF + B*N)        // B*NCH*2 per-chunk (max, sumexp)
#define PSUM_OFF   (MS_OFF + B*NCH*2)       // B*NCH per-chunk pow partial sums
#define PART_OFF   (PSUM_OFF + B*NCH)       // GRID*64 r partials (unnormalized)

// 16-lane (DPP row) sum reduction: row_ror 8,4,2,1. All 16 lanes end with the sum.
__device__ __forceinline__ float rowsum16(float x) {
    float t;
    t = __int_as_float(__builtin_amdgcn_update_dpp(0, __float_as_int(x), 0x128, 0xF, 0xF, true)); x += t;
    t = __int_as_float(__builtin_amdgcn_update_dpp(0, __float_as_int(x), 0x124, 0xF, 0xF, true)); x += t;
    t = __int_as_float(__builtin_amdgcn_update_dpp(0, __float_as_int(x), 0x122, 0xF, 0xF, true)); x += t;
    t = __int_as_float(__builtin_amdgcn_update_dpp(0, __float_as_int(x), 0x121, 0xF, 0xF, true)); x += t;
    return x;
}

// ---------- K1: o = c@W.T + b, activations ----------
__global__ __launch_bounds__(256) void k1(const float* __restrict__ c,
                                          const float* __restrict__ W,
                                          const float* __restrict__ bias,
                                          float* __restrict__ ws) {
    int b = blockIdx.x;
    __shared__ float cs[DDIM];
    __shared__ float osh[72];
    int tid = threadIdx.x;
    for (int i = tid; i < DDIM; i += 256) cs[i] = c[b * DDIM + i];
    __syncthreads();
    int wave = tid >> 6, lane = tid & 63;
    for (int j = wave; j < MDIM + 6; j += 4) {
        const float* wr = W + (size_t)j * DDIM;
        float sum = 0.f;
        for (int d = lane; d < DDIM; d += 64) sum += cs[d] * wr[d];
        for (int off = 32; off > 0; off >>= 1) sum += __shfl_xor(sum, off);
        if (lane == 0) osh[j] = sum + bias[j];
    }
    __syncthreads();
    if (tid < 64) ws[K_OFF + b * 64 + tid] = osh[tid];
    if (wave == 0) {
        float v = osh[lane];
        float sq = v * v;
        for (int off = 32; off > 0; off >>= 1) sq += __shfl_xor(sq, off);
        if (lane == 0) {
            float kn = sqrtf(sq);
            float ob = osh[64], og = osh[65], os0 = osh[66], os1 = osh[67],
                  os2 = osh[68], ogm = osh[69];
            float beta  = fmaxf(ob, 0.f) + log1pf(expf(-fabsf(ob)));
            float g     = 1.f / (1.f + expf(-og));
            float mx    = fmaxf(os0, fmaxf(os1, os2));
            float e0 = expf(os0 - mx), e1 = expf(os1 - mx), e2 = expf(os2 - mx);
            float es = e0 + e1 + e2;
            float gamma = 1.f + fmaxf(ogm, 0.f) + log1pf(expf(-fabsf(ogm)));
            float* sc = ws + SCAL_OFF + b * 8;
            sc[0] = kn; sc[1] = beta; sc[2] = g;
            sc[3] = e0 / es; sc[4] = e1 / es; sc[5] = e2 / es;
            sc[6] = gamma;
        }
    }
}

// ---------- K2: scores + per-chunk softmax stats ----------
__global__ __launch_bounds__(256, 8) void k2(const float* __restrict__ mem,
                                             float* __restrict__ ws) {
    int b = blockIdx.x >> 5, chunk = blockIdx.x & 31;
    __shared__ float ks[64];
    __shared__ float kb2[2];
    __shared__ float scbuf[CHUNK];
    int tid = threadIdx.x;
    if (tid < 64) ks[tid] = ws[K_OFF + b * 64 + tid];
    if (tid == 64) kb2[0] = ws[SCAL_OFF + b * 8 + 0];
    if (tid == 65) kb2[1] = ws[SCAL_OFF + b * 8 + 1];
    __syncthreads();
    float kn = kb2[0], beta = kb2[1];
    int grp = tid >> 4, ll = tid & 15;
    float k0 = ks[ll * 4], k1v = ks[ll * 4 + 1], k2v = ks[ll * 4 + 2], k3v = ks[ll * 4 + 3];
    int row0 = chunk * CHUNK;
    #pragma unroll 8
    for (int it = 0; it < CHUNK / 16; ++it) {
        int lrow = it * 16 + grp;
        float4 v = *reinterpret_cast<const float4*>(
            mem + ((size_t)b * N + row0 + lrow) * MDIM + ll * 4);
        float dot = v.x * k0 + v.y * k1v + v.z * k2v + v.w * k3v;
        float sq  = v.x * v.x + v.y * v.y + v.z * v.z + v.w * v.w;
        dot = rowsum16(dot);
        sq  = rowsum16(sq);
        if (ll == 0)
            scbuf[lrow] = beta * (dot / (kn * sqrtf(sq) + EPSF));
    }
    __syncthreads();
    // coalesced score write + chunk stats from wave 0
    {
        float s0v = scbuf[tid], s1v = scbuf[tid + 256];
        float* sco = ws + SCORE_OFF + (size_t)b * N + row0;
        sco[tid] = s0v;
        sco[tid + 256] = s1v;
    }
    if (tid < 64) {
        float vr[8];
        float m = -1e30f;
        #pragma unroll
        for (int j = 0; j < 8; ++j) {
            vr[j] = scbuf[tid + 64 * j];
            m = fmaxf(m, vr[j]);
        }
        #pragma unroll
        for (int off = 32; off > 0; off >>= 1) m = fmaxf(m, __shfl_xor(m, off));
        float s = 0.f;
        #pragma unroll
        for (int j = 0; j < 8; ++j) s += __expf(vr[j] - m);
        #pragma unroll
        for (int off = 32; off > 0; off >>= 1) s += __shfl_xor(s, off);
        if (tid == 0) {
            ws[MS_OFF + ((size_t)b * NCH + chunk) * 2]     = m;
            ws[MS_OFF + ((size_t)b * NCH + chunk) * 2 + 1] = s;
        }
    }
}

// ---------- KRW: prefetch-pipelined w_g/shift/pow + r-partial memory pass ----------
__global__ __launch_bounds__(256, 8) void krw(const float* __restrict__ mem,
                                              const float* __restrict__ w_prev,
                                              float* __restrict__ ws,
                                              float* __restrict__ w_out,
                                              float* __restrict__ part) {
    int b = blockIdx.x >> 5, chunk = blockIdx.x & 31;
    int tid = threadIdx.x, wave = tid >> 6, lane = tid & 63;
    int grp = tid >> 4, ll = tid & 15;
    __shared__ float wgL[CHUNK + 2];   // w_g halo buffer
    __shared__ float wpl[CHUNK];       // w_pow (unnormalized)
    __shared__ float lds[16][64];      // r partial reduce
    __shared__ float red[4];
    int row0 = chunk * CHUNK;

    // ---- issue first mem loads BEFORE the prologue (keep HBM busy) ----
    const f4* mbase = (const f4*)(mem + ((size_t)b * N + row0 + grp) * MDIM + ll * 4);
    // row it*16+grp -> offset (it*16)*MDIM floats = it*256 f4's
    f4 pre[4];
    #pragma unroll
    for (int j = 0; j < 4; ++j)
        pre[j] = __builtin_nontemporal_load(mbase + j * 256);

    const float* sl = ws + SCAL_OFF + b * 8;
    float g = sl[2], s0 = sl[3], s1 = sl[4], s2 = sl[5], gamma = sl[6];

    // ---- wave-parallel online-softmax combine (lanes 0..31 hold pairs) ----
    const float* msp = ws + MS_OFF + (size_t)b * NCH * 2;
    float mi = -1e30f, si = 0.f;
    if (lane < NCH) {
        mi = msp[lane * 2];
        si = msp[lane * 2 + 1];
    }
    #pragma unroll
    for (int off = 32; off > 0; off >>= 1) {
        float m2 = __shfl_xor(mi, off), s2x = __shfl_xor(si, off);
        float M = fmaxf(mi, m2);
        si = si * __expf(mi - M) + s2x * __expf(m2 - M);
        mi = M;
    }
    float mx = mi;
    float inv = 1.f / si;

    const float* sc = ws + SCORE_OFF + (size_t)b * N;
    const float* wp = w_prev + (size_t)b * N;

    // w_g(row) = g * softmax + (1-g) * w_prev, rows row0-1 .. row0+CHUNK
    {
        int r0 = row0 + tid;
        wgL[tid + 1]   = g * (__expf(sc[r0] - mx) * inv) + (1.f - g) * wp[r0];
        int r1 = row0 + tid + 256;
        wgL[tid + 257] = g * (__expf(sc[r1] - mx) * inv) + (1.f - g) * wp[r1];
        if (tid == 0) {
            int rl = (row0 - 1) & (N - 1);
            wgL[0] = g * (__expf(sc[rl] - mx) * inv) + (1.f - g) * wp[rl];
        }
        if (tid == 255) {
            int rr = (row0 + CHUNK) & (N - 1);
            wgL[CHUNK + 1] = g * (__expf(sc[rr] - mx) * inv) + (1.f - g) * wp[rr];
        }
    }
    __syncthreads();

    // shift + pow; stage w_pow in LDS and to w_out (unnormalized)
    float wt0 = s0 * wgL[tid]       + s1 * wgL[tid + 1]   + s2 * wgL[tid + 2];
    float wt1 = s0 * wgL[tid + 256] + s1 * wgL[tid + 257] + s2 * wgL[tid + 258];
    float p0 = __expf(gamma * __logf(wt0));   // wt in (0,1]; ->0 correctly
    float p1 = __expf(gamma * __logf(wt1));
    wpl[tid] = p0;
    wpl[tid + 256] = p1;
    float* wo = w_out + (size_t)b * N + row0;
    wo[tid]       = p0;
    wo[tid + 256] = p1;

    // per-chunk pow-sum
    float sp = p0 + p1;
    #pragma unroll
    for (int off = 32; off > 0; off >>= 1) sp += __shfl_xor(sp, off);
    if (lane == 0) red[wave] = sp;
    __syncthreads();
    if (tid == 0)
        ws[PSUM_OFF + (size_t)b * NCH + chunk] = red[0] + red[1] + red[2] + red[3];

    // ---- memory pass: software-pipelined, nontemporal (last use of mem) ----
    f4 acc = (f4)(0.f);
    #pragma unroll
    for (int it = 0; it < CHUNK / 16; ++it) {
        f4 v = pre[it & 3];
        int nxt = it + 4;
        if (nxt < CHUNK / 16)
            pre[it & 3] = __builtin_nontemporal_load(mbase + nxt * 256);
        float wv = wpl[it * 16 + grp];
        acc += wv * v;
    }
    lds[grp][ll * 4 + 0] = acc.x;
    lds[grp][ll * 4 + 1] = acc.y;
    lds[grp][ll * 4 + 2] = acc.z;
    lds[grp][ll * 4 + 3] = acc.w;
    __syncthreads();
    if (tid < 64) {
        float sacc = 0.f;
        #pragma unroll
        for (int gi = 0; gi < 16; ++gi) sacc += lds[gi][tid];
        part[(size_t)blockIdx.x * 64 + tid] = sacc;
    }
}

// ---------- KFIN: invp; finalize w in place; chunk-0 blocks also emit r ----------
__global__ __launch_bounds__(256) void kfin(const float* __restrict__ part,
                                            float* __restrict__ ws,
                                            float* __restrict__ w_out,
                                            float* __restrict__ r) {
    int b = blockIdx.x >> 5, chunk = blockIdx.x & 31;
    int tid = threadIdx.x;
    __shared__ float invps;
    if (tid < 64) {
        float s = (tid < 32) ? ws[PSUM_OFF + (size_t)b * NCH + tid] : 0.f;
        #pragma unroll
        for (int off = 32; off > 0; off >>= 1) s += __shfl_xor(s, off);
        if (tid == 0) invps = 1.f / (s + EPSF);
    }
    __syncthreads();
    float invp = invps;
    size_t base = (size_t)b * N + chunk * CHUNK;
    w_out[base + tid]       *= invp;
    w_out[base + tid + 256] *= invp;
    if (chunk == 0 && tid < 64) {
        float srr = 0.f;
        #pragma unroll
        for (int c2 = 0; c2 < NCH; ++c2)
            srr += part[((size_t)b * NCH + c2) * 64 + tid];
        r[b * 64 + tid] = srr * invp;
    }
}

extern "C" void kernel_launch(void* const* d_in, const int* in_sizes, int n_in,
                              void* d_out, int out_size, void* d_ws, size_t ws_size,
                              hipStream_t stream) {
    const float* c      = (const float*)d_in[0];
    const float* w_prev = (const float*)d_in[1];
    const float* mem    = (const float*)d_in[2];
    const float* W      = (const float*)d_in[3];
    const float* bias   = (const float*)d_in[4];
    float* out = (float*)d_out;
    float* r_out = out;                 // B*M
    float* w_out = out + B * MDIM;      // B*N (staged as w_pow, finalized by kfin)
    float* ws = (float*)d_ws;
    float* part = ws + PART_OFF;

    k1  <<<B,    256, 0, stream>>>(c, W, bias, ws);
    k2  <<<GRID, 256, 0, stream>>>(mem, ws);
    krw <<<GRID, 256, 0, stream>>>(mem, w_prev, ws, w_out, part);
    kfin<<<GRID, 256, 0, stream>>>(part, ws, w_out, r_out);
}